// Round 18
// baseline (146.577 us; speedup 1.0000x reference)
//
#include <hip/hip_runtime.h>
#include <math.h>

#define RES 2048
#define NB  256
#define PLANE (RES * NB)       // 524288 f16 per plane (1 MB)
#define STEP (2.0f / 2047.0f)

// DIAGNOSTIC: gemm_lds runs its whole body REP times (idempotent stores).
// dur = T + REP*G + OH with R17's T + G = 12.3, OH ~9.8 -> solves T and G;
// the ~16G-long gemm dispatch finally surfaces in rocprof's top-5.
#define REP 16

typedef _Float16 f16;
typedef _Float16 f16x8 __attribute__((ext_vector_type(8)));
typedef float    f32x16 __attribute__((ext_vector_type(16)));

#define AS1 __attribute__((address_space(1)))
#define AS3 __attribute__((address_space(3)))

__device__ __forceinline__ void g2l16(const void* g, void* l) {
    __builtin_amdgcn_global_load_lds((const AS1 void*)g, (AS3 void*)l, 16, 0, 0);
}

__device__ __forceinline__ f16x8 neg8(f16x8 v) {
    union { f16x8 h; unsigned int u[4]; } x;
    x.h = v;
    #pragma unroll
    for (int i = 0; i < 4; ++i) x.u[i] ^= 0x80008000u;
    return x.h;
}

// ---------------------------------------------------------------------------
// Kernel 1: frag-ordered tables (identical to R17).
// ---------------------------------------------------------------------------
__global__ __launch_bounds__(256) void tables_frag(
    const float* __restrict__ theta, const float* __restrict__ reA,
    const float* __restrict__ imA, const float* __restrict__ x0A,
    const float* __restrict__ y0A, const float* __restrict__ lsA,
    f16* __restrict__ ws)
{
    __shared__ float4 sP0[NB];   // {kx, ky, px, py}
    __shared__ float4 sP1[NB];   // {re, im, is2, -}

    const int t = threadIdx.x;
    {
        const int b = t;
        const float th = theta[b];
        const float s = __sinf(th), c = __cosf(th);
        const float sig = __expf(lsA[b]) + 0.001f;
        sP0[b] = make_float4(50.0f * c, 50.0f * s, x0A[b], y0A[b]);
        sP1[b] = make_float4(reA[b], imA[b], 1.0f / (sig * sig), 0.0f);
    }
    __syncthreads();

    f16* aRe = ws;
    f16* aIm = ws + PLANE;
    f16* bRe = ws + 2 * PLANE;
    f16* bIm = ws + 3 * PLANE;

    const int gid = blockIdx.x * 256 + t;
    const int l   = gid & 63;
    const int w   = gid >> 6;              // chunk id 0..1023
    const int grow = (w >> 4) * 32 + (l & 31);
    const int b0   = (w & 15) * 16 + (l >> 5) * 8;
    const int e    = w * 512 + (l >> 5) * 256 + (l & 31) * 8;

    const float xv = -1.0f + (float)grow * STEP;

    float aRv[8], aIv[8], bRv[8], bIv[8];
    #pragma unroll
    for (int j = 0; j < 8; ++j) {
        const int b = b0 + j;
        const float4 p0 = sP0[b];
        const float4 p1 = sP1[b];

        const float phx = p0.x * xv;
        const float snx = __sinf(phx), csx = __cosf(phx);
        const float dx = xv - p0.z;
        const float ex = __expf(-dx * dx * p1.z);
        aRv[j] = ex * (p1.x * csx - p1.y * snx);
        aIv[j] = ex * (p1.x * snx + p1.y * csx);

        const float phy = p0.y * xv;
        const float sny = __sinf(phy), csy = __cosf(phy);
        const float dy = xv - p0.w;
        const float ey = __expf(-dy * dy * p1.z);
        bRv[j] = ey * csy;
        bIv[j] = ey * sny;
    }

    union { f16 h[8]; float4 v; } p;
    #pragma unroll
    for (int j = 0; j < 8; ++j) p.h[j] = (f16)aRv[j];
    *(float4*)&aRe[e] = p.v;
    #pragma unroll
    for (int j = 0; j < 8; ++j) p.h[j] = (f16)aIv[j];
    *(float4*)&aIm[e] = p.v;
    #pragma unroll
    for (int j = 0; j < 8; ++j) p.h[j] = (f16)bRv[j];
    *(float4*)&bRe[e] = p.v;
    #pragma unroll
    for (int j = 0; j < 8; ++j) p.h[j] = (f16)bIv[j];
    *(float4*)&bIm[e] = p.v;
}

// ---------------------------------------------------------------------------
// Kernel 2: R17 gemm_lds with internal REP loop (diagnostic).
// ---------------------------------------------------------------------------
__global__ __launch_bounds__(256) void gemm_lds(
    const f16* __restrict__ ws, float* __restrict__ out)
{
    __shared__ f16 lds[2][12 * 512];

    const int t    = threadIdx.x;
    const int lane = t & 63;
    const int wave = t >> 6;
    const int la   = lane & 31;
    const int lg   = lane >> 5;

    const int flat = blockIdx.x;
    const int swz  = (flat & 7) * 64 + (flat >> 3);
    const int mb   = swz >> 4;
    const int nb   = swz & 15;
    const int m0   = mb * 64;
    const int n0   = nb * 128;

    const f16* gsrc[3];
    int ldst[3];
    #pragma unroll
    for (int j = 0; j < 3; ++j) {
        const int idx = wave + 4 * j;
        int p, rb;
        if (idx < 2)      { p = 0; rb = (m0 >> 5) + idx; }
        else if (idx < 4) { p = 1; rb = (m0 >> 5) + (idx - 2); }
        else if (idx < 8) { p = 2; rb = (n0 >> 5) + (idx - 4); }
        else              { p = 3; rb = (n0 >> 5) + (idx - 8); }
        gsrc[j] = ws + (size_t)p * PLANE + rb * 16 * 512 + lane * 8;
        ldst[j] = idx * 512;
    }

    #define STAGE(bf, kt)                                                     \
    do {                                                                      \
        g2l16(gsrc[0] + (kt) * 512, &lds[bf][ldst[0]]);                       \
        g2l16(gsrc[1] + (kt) * 512, &lds[bf][ldst[1]]);                       \
        g2l16(gsrc[2] + (kt) * 512, &lds[bf][ldst[2]]);                       \
    } while (0)

    const int lo   = lane * 8;
    const int oAR0 = 0 * 512 + lo, oAR1 = 1 * 512 + lo;
    const int oAI0 = 2 * 512 + lo, oAI1 = 3 * 512 + lo;
    const int oBR  = (4 + wave) * 512 + lo;
    const int oBI  = (8 + wave) * 512 + lo;

    const int gn = n0 + wave * 32 + la;

    for (int rep = 0; rep < REP; ++rep) {
        f32x16 accRe0 = (f32x16)0.0f, accIm0 = (f32x16)0.0f;
        f32x16 accRe1 = (f32x16)0.0f, accIm1 = (f32x16)0.0f;

        STAGE(0, 0);
        __syncthreads();

        for (int kt = 0; kt < 16; ++kt) {
            const int cur = kt & 1;
            if (kt + 1 < 16)
                STAGE(cur ^ 1, kt + 1);

            const f16* s = lds[cur];
            const f16x8 aR0 = *(const f16x8*)(s + oAR0);
            const f16x8 aR1 = *(const f16x8*)(s + oAR1);
            const f16x8 aI0 = *(const f16x8*)(s + oAI0);
            const f16x8 aI1 = *(const f16x8*)(s + oAI1);
            const f16x8 bR  = *(const f16x8*)(s + oBR);
            const f16x8 bI  = *(const f16x8*)(s + oBI);
            const f16x8 bN  = neg8(bI);

            __builtin_amdgcn_s_setprio(1);
            accRe0 = __builtin_amdgcn_mfma_f32_32x32x16_f16(aR0, bR, accRe0, 0, 0, 0);
            accIm0 = __builtin_amdgcn_mfma_f32_32x32x16_f16(aR0, bI, accIm0, 0, 0, 0);
            accRe1 = __builtin_amdgcn_mfma_f32_32x32x16_f16(aR1, bR, accRe1, 0, 0, 0);
            accIm1 = __builtin_amdgcn_mfma_f32_32x32x16_f16(aR1, bI, accIm1, 0, 0, 0);
            accRe0 = __builtin_amdgcn_mfma_f32_32x32x16_f16(aI0, bN, accRe0, 0, 0, 0);
            accIm0 = __builtin_amdgcn_mfma_f32_32x32x16_f16(aI0, bR, accIm0, 0, 0, 0);
            accRe1 = __builtin_amdgcn_mfma_f32_32x32x16_f16(aI1, bN, accRe1, 0, 0, 0);
            accIm1 = __builtin_amdgcn_mfma_f32_32x32x16_f16(aI1, bR, accIm1, 0, 0, 0);
            __builtin_amdgcn_s_setprio(0);

            __syncthreads();
        }

        #pragma unroll
        for (int r = 0; r < 16; ++r) {
            const int row = (r & 3) + 8 * (r >> 2) + 4 * lg;
            const float er = accRe0[r], ei = accIm0[r];
            out[(size_t)(m0 + row) * RES + gn] = er * er + ei * ei;
        }
        #pragma unroll
        for (int r = 0; r < 16; ++r) {
            const int row = (r & 3) + 8 * (r >> 2) + 4 * lg;
            const float er = accRe1[r], ei = accIm1[r];
            out[(size_t)(m0 + 32 + row) * RES + gn] = er * er + ei * ei;
        }
    }
    #undef STAGE
}

// ---------------------------------------------------------------------------
__global__ __launch_bounds__(256) void ewald_direct(
    const float* __restrict__ theta, const float* __restrict__ reA,
    const float* __restrict__ imA, const float* __restrict__ x0A,
    const float* __restrict__ y0A, const float* __restrict__ lsA,
    const float* __restrict__ X, const float* __restrict__ Y,
    float* __restrict__ out)
{
    __shared__ float kxs[NB], kys[NB], res[NB], ims[NB], pxs[NB], pys[NB], is2s[NB];
    const int t = threadIdx.x;
    if (t < NB) {
        const float th  = theta[t];
        const float sig = __expf(lsA[t]) + 0.001f;
        kxs[t] = 50.0f * __cosf(th);
        kys[t] = 50.0f * __sinf(th);
        res[t] = reA[t]; ims[t] = imA[t];
        pxs[t] = x0A[t]; pys[t] = y0A[t];
        is2s[t] = 1.0f / (sig * sig);
    }
    __syncthreads();
    const size_t npix = (size_t)RES * RES;
    for (size_t idx = (size_t)blockIdx.x * blockDim.x + t; idx < npix;
         idx += (size_t)gridDim.x * blockDim.x) {
        const float xv = X[idx], yv = Y[idx];
        float er = 0.f, ei = 0.f;
        for (int b = 0; b < NB; ++b) {
            const float dx = xv - pxs[b], dy = yv - pys[b];
            const float env = __expf(-(dx * dx + dy * dy) * is2s[b]);
            const float ph = kxs[b] * xv + kys[b] * yv;
            float s, c;
            __sincosf(ph, &s, &c);
            er += env * (res[b] * c - ims[b] * s);
            ei += env * (res[b] * s + ims[b] * c);
        }
        out[idx] = er * er + ei * ei;
    }
}

// ---------------------------------------------------------------------------
extern "C" void kernel_launch(void* const* d_in, const int* in_sizes, int n_in,
                              void* d_out, int out_size, void* d_ws, size_t ws_size,
                              hipStream_t stream) {
    const float* theta = (const float*)d_in[0];
    const float* reA   = (const float*)d_in[1];
    const float* imA   = (const float*)d_in[2];
    const float* x0A   = (const float*)d_in[3];
    const float* y0A   = (const float*)d_in[4];
    const float* lsA   = (const float*)d_in[5];
    const float* X     = (const float*)d_in[6];
    const float* Y     = (const float*)d_in[7];
    float* out = (float*)d_out;

    const size_t need = 4 * (size_t)PLANE * sizeof(f16);   // 4 MB

    if (ws_size >= need) {
        f16* ws = (f16*)d_ws;
        tables_frag<<<256, 256, 0, stream>>>(theta, reA, imA, x0A, y0A, lsA, ws);
        gemm_lds<<<512, 256, 0, stream>>>(ws, out);
    } else {
        ewald_direct<<<2048, 256, 0, stream>>>(theta, reA, imA, x0A, y0A, lsA,
                                               X, Y, out);
    }
}

// Round 19
// 22.925 us; speedup vs baseline: 6.3938x; 6.3938x over previous
//
#include <hip/hip_runtime.h>
#include <math.h>

#define RES 2048
#define NB  256
#define PLANE (RES * NB)       // 524288 f16 per plane (1 MB)
#define STEP (2.0f / 2047.0f)

typedef _Float16 f16;
typedef _Float16 f16x8 __attribute__((ext_vector_type(8)));
typedef float    f32x16 __attribute__((ext_vector_type(16)));

#define AS1 __attribute__((address_space(1)))
#define AS3 __attribute__((address_space(3)))

__device__ __forceinline__ void g2l16(const void* g, void* l) {
    __builtin_amdgcn_global_load_lds((const AS1 void*)g, (AS3 void*)l, 16, 0, 0);
}

// ---------------------------------------------------------------------------
// Kernel 1: frag-ordered tables. R18 diag: T was 4.0 us at 1 wave/SIMD ->
// double TLP: 512 blocks x 256 threads, each thread does 4 beams (half of
// R17). value(row,b) at e = chunk*512 + (b&15)>>3*256... (R15-verified map).
// ---------------------------------------------------------------------------
__global__ __launch_bounds__(256) void tables_frag(
    const float* __restrict__ theta, const float* __restrict__ reA,
    const float* __restrict__ imA, const float* __restrict__ x0A,
    const float* __restrict__ y0A, const float* __restrict__ lsA,
    f16* __restrict__ ws)
{
    __shared__ float4 sP0[NB];   // {kx, ky, px, py}
    __shared__ float4 sP1[NB];   // {re, im, is2, -}

    const int t = threadIdx.x;
    {
        const int b = t;
        const float th = theta[b];
        const float s = __sinf(th), c = __cosf(th);
        const float sig = __expf(lsA[b]) + 0.001f;
        sP0[b] = make_float4(50.0f * c, 50.0f * s, x0A[b], y0A[b]);
        sP1[b] = make_float4(reA[b], imA[b], 1.0f / (sig * sig), 0.0f);
    }
    __syncthreads();

    f16* aRe = ws;
    f16* aIm = ws + PLANE;
    f16* bRe = ws + 2 * PLANE;
    f16* bIm = ws + 3 * PLANE;

    const int gid   = blockIdx.x * 256 + t;   // 0..131071
    const int l     = gid & 63;
    const int w2    = gid >> 6;               // 0..2047
    const int chunk = w2 >> 1;                // 0..1023
    const int half  = w2 & 1;
    const int grow  = (chunk >> 4) * 32 + (l & 31);
    const int b0    = (chunk & 15) * 16 + (l >> 5) * 8 + half * 4;
    const int e     = chunk * 512 + (l >> 5) * 256 + (l & 31) * 8 + half * 4;

    const float xv = -1.0f + (float)grow * STEP;

    float aRv[4], aIv[4], bRv[4], bIv[4];
    #pragma unroll
    for (int j = 0; j < 4; ++j) {
        const int b = b0 + j;
        const float4 p0 = sP0[b];
        const float4 p1 = sP1[b];

        const float phx = p0.x * xv;
        const float snx = __sinf(phx), csx = __cosf(phx);
        const float dx = xv - p0.z;
        const float ex = __expf(-dx * dx * p1.z);
        aRv[j] = ex * (p1.x * csx - p1.y * snx);
        aIv[j] = ex * (p1.x * snx + p1.y * csx);

        const float phy = p0.y * xv;
        const float sny = __sinf(phy), csy = __cosf(phy);
        const float dy = xv - p0.w;
        const float ey = __expf(-dy * dy * p1.z);
        bRv[j] = ey * csy;
        bIv[j] = ey * sny;
    }

    union { f16 h[4]; float2 v; } p;
    #pragma unroll
    for (int j = 0; j < 4; ++j) p.h[j] = (f16)aRv[j];
    *(float2*)&aRe[e] = p.v;
    #pragma unroll
    for (int j = 0; j < 4; ++j) p.h[j] = (f16)aIv[j];
    *(float2*)&aIm[e] = p.v;
    #pragma unroll
    for (int j = 0; j < 4; ++j) p.h[j] = (f16)bRv[j];
    *(float2*)&bRe[e] = p.v;
    #pragma unroll
    for (int j = 0; j < 4; ++j) p.h[j] = (f16)bIv[j];
    *(float2*)&bIm[e] = p.v;
}

// ---------------------------------------------------------------------------
// Kernel 2: complex GEMM. R18 counters: MfmaUtil 46%, VALU 15%, ~40% stall
// (per-kt vmcnt(0) drain). Fixes:
//  (a) T4 counted-vmcnt 3-buffer pipeline: raw s_barrier + per-wave
//      s_waitcnt vmcnt(3), depth-2 prefetch -> the wait covers loads issued
//      2 tiles ago (landed long ago), never the just-issued ones. All waves
//      run the same schedule, so own-vmcnt + barrier => data visible.
//      Uniform loop via wrap-around garbage stages (tiles (kt+2)&15; writes
//      target a buffer whose reads finished at kt-1 -> race-free).
//  (b) Gauss 3-MFMA complex: T1=aR.bR, T2=aI.bI, T3=(aR+aI).(bR+bI);
//      Re=T1-T2, Im=T3-T1-T2. 6 MFMA/kt instead of 8.
// 64x128 tile, 512 blocks = 2/CU, 4 waves, 36 KB LDS.
// ---------------------------------------------------------------------------
__global__ __launch_bounds__(256) void gemm_lds(
    const f16* __restrict__ ws, float* __restrict__ out)
{
    __shared__ f16 lds[3][12 * 512];   // 36 KB

    const int t    = threadIdx.x;
    const int lane = t & 63;
    const int wave = t >> 6;       // 0..3 = N sub-tile
    const int la   = lane & 31;
    const int lg   = lane >> 5;

    // XCD swizzle: 512 blocks, 8 XCDs, 64 contiguous per XCD
    const int flat = blockIdx.x;
    const int swz  = (flat & 7) * 64 + (flat >> 3);
    const int m0   = (swz >> 4) * 64;
    const int n0   = (swz & 15) * 128;

    // staging map: 12 chunks/kt, 3 per wave
    const f16* gsrc[3];
    int ldst[3];
    #pragma unroll
    for (int j = 0; j < 3; ++j) {
        const int idx = wave + 4 * j;
        int p, rb;
        if (idx < 2)      { p = 0; rb = (m0 >> 5) + idx; }
        else if (idx < 4) { p = 1; rb = (m0 >> 5) + (idx - 2); }
        else if (idx < 8) { p = 2; rb = (n0 >> 5) + (idx - 4); }
        else              { p = 3; rb = (n0 >> 5) + (idx - 8); }
        gsrc[j] = ws + (size_t)p * PLANE + rb * 16 * 512 + lane * 8;
        ldst[j] = idx * 512;
    }

    #define STAGE(bf, kt)                                                     \
    do {                                                                      \
        g2l16(gsrc[0] + (kt) * 512, &lds[0][0] + (bf) * 6144 + ldst[0]);      \
        g2l16(gsrc[1] + (kt) * 512, &lds[0][0] + (bf) * 6144 + ldst[1]);      \
        g2l16(gsrc[2] + (kt) * 512, &lds[0][0] + (bf) * 6144 + ldst[2]);      \
    } while (0)

    const int lo   = lane * 8;
    const int oAR0 = 0 * 512 + lo, oAR1 = 1 * 512 + lo;
    const int oAI0 = 2 * 512 + lo, oAI1 = 3 * 512 + lo;
    const int oBR  = (4 + wave) * 512 + lo;
    const int oBI  = (8 + wave) * 512 + lo;

    f32x16 t1_0 = (f32x16)0.0f, t2_0 = (f32x16)0.0f, t3_0 = (f32x16)0.0f;
    f32x16 t1_1 = (f32x16)0.0f, t2_1 = (f32x16)0.0f, t3_1 = (f32x16)0.0f;

    // prologue: depth-2 prefetch
    STAGE(0, 0);
    STAGE(1, 1);

    int cur = 0;
    for (int kt = 0; kt < 16; ++kt) {
        // own oldest loads (tile kt) landed; tile kt+1's 3 may stay in flight
        asm volatile("s_waitcnt vmcnt(3)" ::: "memory");
        __builtin_amdgcn_s_barrier();

        // stage tile kt+2 (wrap: garbage tiles at the end, race-free)
        int nx = cur - 1; if (nx < 0) nx += 3;        // (cur+2)%3
        STAGE(nx, (kt + 2) & 15);

        const f16* s = &lds[0][0] + cur * 6144;
        const f16x8 aR0 = *(const f16x8*)(s + oAR0);
        const f16x8 aR1 = *(const f16x8*)(s + oAR1);
        const f16x8 aI0 = *(const f16x8*)(s + oAI0);
        const f16x8 aI1 = *(const f16x8*)(s + oAI1);
        const f16x8 bR  = *(const f16x8*)(s + oBR);
        const f16x8 bI  = *(const f16x8*)(s + oBI);
        const f16x8 aS0 = aR0 + aI0;
        const f16x8 aS1 = aR1 + aI1;
        const f16x8 bS  = bR + bI;

        __builtin_amdgcn_s_setprio(1);
        t1_0 = __builtin_amdgcn_mfma_f32_32x32x16_f16(aR0, bR, t1_0, 0, 0, 0);
        t2_0 = __builtin_amdgcn_mfma_f32_32x32x16_f16(aI0, bI, t2_0, 0, 0, 0);
        t3_0 = __builtin_amdgcn_mfma_f32_32x32x16_f16(aS0, bS, t3_0, 0, 0, 0);
        t1_1 = __builtin_amdgcn_mfma_f32_32x32x16_f16(aR1, bR, t1_1, 0, 0, 0);
        t2_1 = __builtin_amdgcn_mfma_f32_32x32x16_f16(aI1, bI, t2_1, 0, 0, 0);
        t3_1 = __builtin_amdgcn_mfma_f32_32x32x16_f16(aS1, bS, t3_1, 0, 0, 0);
        __builtin_amdgcn_s_setprio(0);

        cur = cur + 1 == 3 ? 0 : cur + 1;
    }

    // epilogue: Re = T1 - T2, Im = T3 - T1 - T2; out = Re^2 + Im^2
    // C/D layout (32x32): col = lane&31, row = (reg&3) + 8*(reg>>2) + 4*(lane>>5)
    const int gn = n0 + wave * 32 + la;
    #pragma unroll
    for (int r = 0; r < 16; ++r) {
        const int row = (r & 3) + 8 * (r >> 2) + 4 * lg;
        const float er = t1_0[r] - t2_0[r];
        const float ei = t3_0[r] - t1_0[r] - t2_0[r];
        out[(size_t)(m0 + row) * RES + gn] = er * er + ei * ei;
    }
    #pragma unroll
    for (int r = 0; r < 16; ++r) {
        const int row = (r & 3) + 8 * (r >> 2) + 4 * lg;
        const float er = t1_1[r] - t2_1[r];
        const float ei = t3_1[r] - t1_1[r] - t2_1[r];
        out[(size_t)(m0 + 32 + row) * RES + gn] = er * er + ei * ei;
    }
    #undef STAGE
}

// ---------------------------------------------------------------------------
// Fallback: direct brute force (only if ws_size too small).
// ---------------------------------------------------------------------------
__global__ __launch_bounds__(256) void ewald_direct(
    const float* __restrict__ theta, const float* __restrict__ reA,
    const float* __restrict__ imA, const float* __restrict__ x0A,
    const float* __restrict__ y0A, const float* __restrict__ lsA,
    const float* __restrict__ X, const float* __restrict__ Y,
    float* __restrict__ out)
{
    __shared__ float kxs[NB], kys[NB], res[NB], ims[NB], pxs[NB], pys[NB], is2s[NB];
    const int t = threadIdx.x;
    if (t < NB) {
        const float th  = theta[t];
        const float sig = __expf(lsA[t]) + 0.001f;
        kxs[t] = 50.0f * __cosf(th);
        kys[t] = 50.0f * __sinf(th);
        res[t] = reA[t]; ims[t] = imA[t];
        pxs[t] = x0A[t]; pys[t] = y0A[t];
        is2s[t] = 1.0f / (sig * sig);
    }
    __syncthreads();
    const size_t npix = (size_t)RES * RES;
    for (size_t idx = (size_t)blockIdx.x * blockDim.x + t; idx < npix;
         idx += (size_t)gridDim.x * blockDim.x) {
        const float xv = X[idx], yv = Y[idx];
        float er = 0.f, ei = 0.f;
        for (int b = 0; b < NB; ++b) {
            const float dx = xv - pxs[b], dy = yv - pys[b];
            const float env = __expf(-(dx * dx + dy * dy) * is2s[b]);
            const float ph = kxs[b] * xv + kys[b] * yv;
            float s, c;
            __sincosf(ph, &s, &c);
            er += env * (res[b] * c - ims[b] * s);
            ei += env * (res[b] * s + ims[b] * c);
        }
        out[idx] = er * er + ei * ei;
    }
}

// ---------------------------------------------------------------------------
extern "C" void kernel_launch(void* const* d_in, const int* in_sizes, int n_in,
                              void* d_out, int out_size, void* d_ws, size_t ws_size,
                              hipStream_t stream) {
    const float* theta = (const float*)d_in[0];
    const float* reA   = (const float*)d_in[1];
    const float* imA   = (const float*)d_in[2];
    const float* x0A   = (const float*)d_in[3];
    const float* y0A   = (const float*)d_in[4];
    const float* lsA   = (const float*)d_in[5];
    const float* X     = (const float*)d_in[6];
    const float* Y     = (const float*)d_in[7];
    float* out = (float*)d_out;

    const size_t need = 4 * (size_t)PLANE * sizeof(f16);   // 4 MB

    if (ws_size >= need) {
        f16* ws = (f16*)d_ws;
        tables_frag<<<512, 256, 0, stream>>>(theta, reA, imA, x0A, y0A, lsA, ws);
        gemm_lds<<<512, 256, 0, stream>>>(ws, out);
    } else {
        ewald_direct<<<2048, 256, 0, stream>>>(theta, reA, imA, x0A, y0A, lsA,
                                               X, Y, out);
    }
}

// Round 20
// 22.168 us; speedup vs baseline: 6.6122x; 1.0342x over previous
//
#include <hip/hip_runtime.h>
#include <math.h>

#define RES 2048
#define NB  256
#define PLANE (RES * NB)       // 524288 f16 per plane (1 MB)
#define STEP (2.0f / 2047.0f)

typedef _Float16 f16;
typedef _Float16 f16x8 __attribute__((ext_vector_type(8)));
typedef float    f32x16 __attribute__((ext_vector_type(16)));

#define AS1 __attribute__((address_space(1)))
#define AS3 __attribute__((address_space(3)))

__device__ __forceinline__ void g2l16(const void* g, void* l) {
    __builtin_amdgcn_global_load_lds((const AS1 void*)g, (AS3 void*)l, 16, 0, 0);
}

__device__ __forceinline__ f16x8 neg8(f16x8 v) {
    union { f16x8 h; unsigned int u[4]; } x;
    x.h = v;
    #pragma unroll
    for (int i = 0; i < 4; ++i) x.u[i] ^= 0x80008000u;
    return x.h;
}

// ---------------------------------------------------------------------------
// Kernel 1: frag-ordered tables, 2 waves/SIMD TLP (R19 version — R18 diag
// showed T = 4.0 us at 1 wave/SIMD, trans-issue-bound).
// value(row,b) at e = chunk*512 + (lane>>5)*256 + (row&31)*8 + (b&7),
// chunk = (row>>5)*16 + (b>>4)  [R15-verified layout].
// ---------------------------------------------------------------------------
__global__ __launch_bounds__(256) void tables_frag(
    const float* __restrict__ theta, const float* __restrict__ reA,
    const float* __restrict__ imA, const float* __restrict__ x0A,
    const float* __restrict__ y0A, const float* __restrict__ lsA,
    f16* __restrict__ ws)
{
    __shared__ float4 sP0[NB];   // {kx, ky, px, py}
    __shared__ float4 sP1[NB];   // {re, im, is2, -}

    const int t = threadIdx.x;
    {
        const int b = t;
        const float th = theta[b];
        const float s = __sinf(th), c = __cosf(th);
        const float sig = __expf(lsA[b]) + 0.001f;
        sP0[b] = make_float4(50.0f * c, 50.0f * s, x0A[b], y0A[b]);
        sP1[b] = make_float4(reA[b], imA[b], 1.0f / (sig * sig), 0.0f);
    }
    __syncthreads();

    f16* aRe = ws;
    f16* aIm = ws + PLANE;
    f16* bRe = ws + 2 * PLANE;
    f16* bIm = ws + 3 * PLANE;

    const int gid   = blockIdx.x * 256 + t;   // 0..131071
    const int l     = gid & 63;
    const int w2    = gid >> 6;               // 0..2047
    const int chunk = w2 >> 1;                // 0..1023
    const int half  = w2 & 1;
    const int grow  = (chunk >> 4) * 32 + (l & 31);
    const int b0    = (chunk & 15) * 16 + (l >> 5) * 8 + half * 4;
    const int e     = chunk * 512 + (l >> 5) * 256 + (l & 31) * 8 + half * 4;

    const float xv = -1.0f + (float)grow * STEP;

    float aRv[4], aIv[4], bRv[4], bIv[4];
    #pragma unroll
    for (int j = 0; j < 4; ++j) {
        const int b = b0 + j;
        const float4 p0 = sP0[b];
        const float4 p1 = sP1[b];

        const float phx = p0.x * xv;
        const float snx = __sinf(phx), csx = __cosf(phx);
        const float dx = xv - p0.z;
        const float ex = __expf(-dx * dx * p1.z);
        aRv[j] = ex * (p1.x * csx - p1.y * snx);
        aIv[j] = ex * (p1.x * snx + p1.y * csx);

        const float phy = p0.y * xv;
        const float sny = __sinf(phy), csy = __cosf(phy);
        const float dy = xv - p0.w;
        const float ey = __expf(-dy * dy * p1.z);
        bRv[j] = ey * csy;
        bIv[j] = ey * sny;
    }

    union { f16 h[4]; float2 v; } p;
    #pragma unroll
    for (int j = 0; j < 4; ++j) p.h[j] = (f16)aRv[j];
    *(float2*)&aRe[e] = p.v;
    #pragma unroll
    for (int j = 0; j < 4; ++j) p.h[j] = (f16)aIv[j];
    *(float2*)&aIm[e] = p.v;
    #pragma unroll
    for (int j = 0; j < 4; ++j) p.h[j] = (f16)bRv[j];
    *(float2*)&bRe[e] = p.v;
    #pragma unroll
    for (int j = 0; j < 4; ++j) p.h[j] = (f16)bIv[j];
    *(float2*)&bIm[e] = p.v;
}

// ---------------------------------------------------------------------------
// Kernel 2: complex GEMM — R17 version VERBATIM (best measured: 22.07 us
// total). 64x128 tile, 512 blocks = 2/CU, 4 waves, 2-buffer double-buffer
// via global_load_lds, one __syncthreads per k-tile, 8 MFMA/kt/wave.
// (R19's counted-vmcnt + Gauss bundle regressed -0.9 us; reverted.)
// ---------------------------------------------------------------------------
__global__ __launch_bounds__(256) void gemm_lds(
    const f16* __restrict__ ws, float* __restrict__ out)
{
    __shared__ f16 lds[2][12 * 512];   // 24 KB

    const int t    = threadIdx.x;
    const int lane = t & 63;
    const int wave = t >> 6;       // 0..3 = N sub-tile
    const int la   = lane & 31;
    const int lg   = lane >> 5;

    // XCD swizzle: 512 blocks, 8 XCDs, 64 contiguous per XCD
    const int flat = blockIdx.x;
    const int swz  = (flat & 7) * 64 + (flat >> 3);
    const int m0   = (swz >> 4) * 64;
    const int n0   = (swz & 15) * 128;

    // staging map: 12 chunks/kt, 3 per wave
    const f16* gsrc[3];
    int ldst[3];
    #pragma unroll
    for (int j = 0; j < 3; ++j) {
        const int idx = wave + 4 * j;
        int p, rb;
        if (idx < 2)      { p = 0; rb = (m0 >> 5) + idx; }
        else if (idx < 4) { p = 1; rb = (m0 >> 5) + (idx - 2); }
        else if (idx < 8) { p = 2; rb = (n0 >> 5) + (idx - 4); }
        else              { p = 3; rb = (n0 >> 5) + (idx - 8); }
        gsrc[j] = ws + (size_t)p * PLANE + rb * 16 * 512 + lane * 8;
        ldst[j] = idx * 512;
    }

    #define STAGE(bf, kt)                                                     \
    do {                                                                      \
        g2l16(gsrc[0] + (kt) * 512, &lds[bf][ldst[0]]);                       \
        g2l16(gsrc[1] + (kt) * 512, &lds[bf][ldst[1]]);                       \
        g2l16(gsrc[2] + (kt) * 512, &lds[bf][ldst[2]]);                       \
    } while (0)

    const int lo   = lane * 8;
    const int oAR0 = 0 * 512 + lo, oAR1 = 1 * 512 + lo;
    const int oAI0 = 2 * 512 + lo, oAI1 = 3 * 512 + lo;
    const int oBR  = (4 + wave) * 512 + lo;
    const int oBI  = (8 + wave) * 512 + lo;

    f32x16 accRe0 = (f32x16)0.0f, accIm0 = (f32x16)0.0f;
    f32x16 accRe1 = (f32x16)0.0f, accIm1 = (f32x16)0.0f;

    STAGE(0, 0);
    __syncthreads();

    for (int kt = 0; kt < 16; ++kt) {
        const int cur = kt & 1;
        if (kt + 1 < 16)
            STAGE(cur ^ 1, kt + 1);

        const f16* s = lds[cur];
        const f16x8 aR0 = *(const f16x8*)(s + oAR0);
        const f16x8 aR1 = *(const f16x8*)(s + oAR1);
        const f16x8 aI0 = *(const f16x8*)(s + oAI0);
        const f16x8 aI1 = *(const f16x8*)(s + oAI1);
        const f16x8 bR  = *(const f16x8*)(s + oBR);
        const f16x8 bI  = *(const f16x8*)(s + oBI);
        const f16x8 bN  = neg8(bI);

        __builtin_amdgcn_s_setprio(1);
        accRe0 = __builtin_amdgcn_mfma_f32_32x32x16_f16(aR0, bR, accRe0, 0, 0, 0);
        accIm0 = __builtin_amdgcn_mfma_f32_32x32x16_f16(aR0, bI, accIm0, 0, 0, 0);
        accRe1 = __builtin_amdgcn_mfma_f32_32x32x16_f16(aR1, bR, accRe1, 0, 0, 0);
        accIm1 = __builtin_amdgcn_mfma_f32_32x32x16_f16(aR1, bI, accIm1, 0, 0, 0);
        accRe0 = __builtin_amdgcn_mfma_f32_32x32x16_f16(aI0, bN, accRe0, 0, 0, 0);
        accIm0 = __builtin_amdgcn_mfma_f32_32x32x16_f16(aI0, bR, accIm0, 0, 0, 0);
        accRe1 = __builtin_amdgcn_mfma_f32_32x32x16_f16(aI1, bN, accRe1, 0, 0, 0);
        accIm1 = __builtin_amdgcn_mfma_f32_32x32x16_f16(aI1, bR, accIm1, 0, 0, 0);
        __builtin_amdgcn_s_setprio(0);

        __syncthreads();
    }

    // epilogue: out = Re^2 + Im^2
    // C/D layout (32x32): col = lane&31, row = (reg&3) + 8*(reg>>2) + 4*(lane>>5)
    const int gn = n0 + wave * 32 + la;
    #pragma unroll
    for (int r = 0; r < 16; ++r) {
        const int row = (r & 3) + 8 * (r >> 2) + 4 * lg;
        const float er = accRe0[r], ei = accIm0[r];
        out[(size_t)(m0 + row) * RES + gn] = er * er + ei * ei;
    }
    #pragma unroll
    for (int r = 0; r < 16; ++r) {
        const int row = (r & 3) + 8 * (r >> 2) + 4 * lg;
        const float er = accRe1[r], ei = accIm1[r];
        out[(size_t)(m0 + 32 + row) * RES + gn] = er * er + ei * ei;
    }
    #undef STAGE
}

// ---------------------------------------------------------------------------
// Fallback: direct brute force (only if ws_size too small).
// ---------------------------------------------------------------------------
__global__ __launch_bounds__(256) void ewald_direct(
    const float* __restrict__ theta, const float* __restrict__ reA,
    const float* __restrict__ imA, const float* __restrict__ x0A,
    const float* __restrict__ y0A, const float* __restrict__ lsA,
    const float* __restrict__ X, const float* __restrict__ Y,
    float* __restrict__ out)
{
    __shared__ float kxs[NB], kys[NB], res[NB], ims[NB], pxs[NB], pys[NB], is2s[NB];
    const int t = threadIdx.x;
    if (t < NB) {
        const float th  = theta[t];
        const float sig = __expf(lsA[t]) + 0.001f;
        kxs[t] = 50.0f * __cosf(th);
        kys[t] = 50.0f * __sinf(th);
        res[t] = reA[t]; ims[t] = imA[t];
        pxs[t] = x0A[t]; pys[t] = y0A[t];
        is2s[t] = 1.0f / (sig * sig);
    }
    __syncthreads();
    const size_t npix = (size_t)RES * RES;
    for (size_t idx = (size_t)blockIdx.x * blockDim.x + t; idx < npix;
         idx += (size_t)gridDim.x * blockDim.x) {
        const float xv = X[idx], yv = Y[idx];
        float er = 0.f, ei = 0.f;
        for (int b = 0; b < NB; ++b) {
            const float dx = xv - pxs[b], dy = yv - pys[b];
            const float env = __expf(-(dx * dx + dy * dy) * is2s[b]);
            const float ph = kxs[b] * xv + kys[b] * yv;
            float s, c;
            __sincosf(ph, &s, &c);
            er += env * (res[b] * c - ims[b] * s);
            ei += env * (res[b] * s + ims[b] * c);
        }
        out[idx] = er * er + ei * ei;
    }
}

// ---------------------------------------------------------------------------
extern "C" void kernel_launch(void* const* d_in, const int* in_sizes, int n_in,
                              void* d_out, int out_size, void* d_ws, size_t ws_size,
                              hipStream_t stream) {
    const float* theta = (const float*)d_in[0];
    const float* reA   = (const float*)d_in[1];
    const float* imA   = (const float*)d_in[2];
    const float* x0A   = (const float*)d_in[3];
    const float* y0A   = (const float*)d_in[4];
    const float* lsA   = (const float*)d_in[5];
    const float* X     = (const float*)d_in[6];
    const float* Y     = (const float*)d_in[7];
    float* out = (float*)d_out;

    const size_t need = 4 * (size_t)PLANE * sizeof(f16);   // 4 MB

    if (ws_size >= need) {
        f16* ws = (f16*)d_ws;
        tables_frag<<<512, 256, 0, stream>>>(theta, reA, imA, x0A, y0A, lsA, ws);
        gemm_lds<<<512, 256, 0, stream>>>(ws, out);
    } else {
        ewald_direct<<<2048, 256, 0, stream>>>(theta, reA, imA, x0A, y0A, lsA,
                                               X, Y, out);
    }
}